// Round 5
// baseline (53.160 us; speedup 1.0000x reference)
//
#include <hip/hip_runtime.h>
#include <cmath>

#define BN 8192
#define DIM 128
#define MARGIN_F 0.3f
#define NSPLIT 8            // column splits (1024 cols each)
#define CPS 1024
#define NT 8                // 128-col B tiles per panel
#define NLAB 128
#define IMAX 0x7FFFFFFF
#define IMIN 0x80000000

typedef __attribute__((ext_vector_type(4))) int i32x4;

__device__ __forceinline__ int imin3(int a, int b, int c) { return min(a, min(b, c)); }
__device__ __forceinline__ int imax3(int a, int b, int c) { return max(a, max(b, c)); }

// ---------------- K0: label histogram + exclusive scan (counting-sort prep) ----------------
// Single block. binStart = exclusive prefix; binCur = running cursor for K1's rank atomics.
__global__ __launch_bounds__(1024) void sort_prep_k(
    const int* __restrict__ lab, int* __restrict__ binStart, int* __restrict__ binCur)
{
  __shared__ int h[16][NLAB];
  int t = threadIdx.x, wv = t >> 6;
  for (int i = t; i < 16 * NLAB; i += 1024) (&h[0][0])[i] = 0;
  __syncthreads();
  for (int i = t; i < BN; i += 1024) atomicAdd(&h[wv][lab[i] & (NLAB - 1)], 1);
  __syncthreads();
  if (t < NLAB) {
    int s = 0;
    #pragma unroll
    for (int w2 = 0; w2 < 16; ++w2) s += h[w2][t];
    h[0][t] = s;
  }
  __syncthreads();
  if (t == 0) {
    int acc = 0;
    for (int b = 0; b < NLAB; ++b) {
      int c = h[0][b];
      binStart[b] = acc; binCur[b] = acc; acc += c;
    }
  }
}

// ---------------- K1: norms + i8 quantize + label-sorted scatter ----------------
// Row r goes to sorted slot dst = atomicAdd(binCur[lab[r]]) (any order within a label is
// valid: mining is min/max over sets). EnQ layout unchanged, just column = dst.
// Also seeds ap_f/an_f sentinels and emits sorted labels labS + sorted sqvS.
__global__ __launch_bounds__(256) void norm_cvt_k(
    const float* __restrict__ emb, const int* __restrict__ lab,
    float* __restrict__ sqvS, unsigned short* __restrict__ EnQ16,
    int* __restrict__ labS, int* __restrict__ binCur,
    int* __restrict__ ap_f, int* __restrict__ an_f)
{
  int gt = blockIdx.x * blockDim.x + threadIdx.x;
  if (gt < BN) { ap_f[gt] = IMAX; an_f[gt] = IMIN; }

  int w = gt >> 6;  // one wave per row
  int lane = threadIdx.x & 63;
  if (w >= BN) return;

  int lb = 0, dst = 0;
  if (lane == 0) { lb = lab[w]; dst = atomicAdd(&binCur[lb], 1); }
  dst = __shfl(dst, 0);
  lb  = __shfl(lb, 0);

  float2 v = *reinterpret_cast<const float2*>(&emb[w * DIM + lane * 2]);
  float s = v.x * v.x + v.y * v.y;
  #pragma unroll
  for (int off = 32; off > 0; off >>= 1) s += __shfl_xor(s, off);
  float iv = 1.0f / fmaxf(sqrtf(s), 1e-12f);
  if (lane == 0) { sqvS[dst] = s * iv * iv; labS[dst] = lb; }
  int q0 = (int)rintf(127.0f * v.x * iv);
  int q1 = (int)rintf(127.0f * v.y * iv);
  unsigned short us = (unsigned short)((q0 & 255) | ((q1 & 255) << 8));
  int g = lane >> 3;                                  // k = 2*lane -> chunk g = lane/8
  EnQ16[(g * BN + dst) * 8 + (lane & 7)] = us;
}

// ---------------- K2: i8-MFMA gram + hard mining with sorted-label fast path ----------------
// Rows/cols label-sorted -> same-label pairs only in a block-diagonal band. Per 64-col tile,
// wave-uniform test [cLo,cHi] x [rLo,rHi]: disjoint (~97% of tiles) -> every pair is a
// negative -> mining is just v_max3 per acc pair (no label loads, no selects). Overlapping
// tiles take the full compare path (with diag self-exclusion). Merge via device atomics.
__global__ __launch_bounds__(256, 2) void gram_mine_mfma_k(
    const char* __restrict__ EnQ, const int* __restrict__ labS,
    int* __restrict__ ap_f, int* __restrict__ an_f)
{
  __shared__ __align__(16) char Bs[2][16384];   // 2 x 16 KB

  const int tid = threadIdx.x;
  const int w = tid >> 6, l = tid & 63;
  const int wr = w >> 1, wc = w & 1;
  const int lrow = l & 15, lkg = l >> 4;

  const int rowBase = blockIdx.x * 128 + wr * 64;   // this wave's 64 rows
  const int panel   = blockIdx.y * CPS;

  // wave-row label range (sorted -> [rLo, rHi] covers exactly the labels present)
  const int rLo = labS[rowBase], rHi = labS[rowBase + 63];

  // A fragments: 4 row-tiles x 2 K-steps (K=64 each), 16B per frag, coalesced
  i32x4 a[4][2];
  #pragma unroll
  for (int mi = 0; mi < 4; ++mi)
    #pragma unroll
    for (int kk = 0; kk < 2; ++kk)
      a[mi][kk] = *reinterpret_cast<const i32x4*>(
          EnQ + (((size_t)((kk << 2) + lkg) * BN + rowBase + mi * 16 + lrow) << 4));

  // byte-packed labels for the 16 rows this lane owns (labels < 128)
  unsigned rlbp[4];
  #pragma unroll
  for (int mi = 0; mi < 4; ++mi) {
    int rb = rowBase + mi * 16 + lkg * 4;
    rlbp[mi] = (unsigned)(labS[rb] & 255) | ((unsigned)(labS[rb + 1] & 255) << 8) |
               ((unsigned)(labS[rb + 2] & 255) << 16) | ((unsigned)(labS[rb + 3] & 255) << 24);
  }

  int ap[4][4], an[4][4];
  #pragma unroll
  for (int mi = 0; mi < 4; ++mi)
    #pragma unroll
    for (int r = 0; r < 4; ++r) { ap[mi][r] = IMAX; an[mi][r] = IMIN; }

  const i32x4 zf = {0, 0, 0, 0};   // shared zero C-operand: no per-half acc zero-init movs

  // async stage of one 128-col tile (1024 slots x 16B): wave w covers [w*256, w*256+256)
  auto stage = [&](int buf, int colTile) {
    #pragma unroll
    for (int i = 0; i < 4; ++i) {
      int s0 = (w << 8) + (i << 6);          // wave-uniform slot base
      int s  = s0 + l;
      const char* gp = EnQ + (((size_t)(s >> 7) * BN + colTile + (s & 127)) << 4);
      __builtin_amdgcn_global_load_lds(
          (const __attribute__((address_space(1))) void*)gp,
          (__attribute__((address_space(3))) void*)(&Bs[buf][s0 * 16]),
          16, 0, 0);
    }
  };

  stage(0, panel);
  __syncthreads();   // drains vmcnt(0) then barrier

  int cur = 0;
  #pragma unroll 1
  for (int ct = 0; ct < NT; ++ct) {
    const int colTile = panel + ct * 128;
    const int colBase = colTile + wc * 64;

    if (ct + 1 < NT) stage(cur ^ 1, colTile + 128);   // in flight during compute

    // wave-uniform tile classification via sorted label ranges
    const int cLo = labS[colBase], cHi = labS[colBase + 63];
    const bool mixed = (cHi >= rLo) && (cLo <= rHi);
    const bool diag  = (rowBase == colBase);          // diag => mixed

    // column labels only needed on the mixed path
    int clb[4];
    if (mixed) {
      #pragma unroll
      for (int ni = 0; ni < 4; ++ni) clb[ni] = labS[colBase + ni * 16 + lrow];
    }

    #pragma unroll
    for (int half = 0; half < 2; ++half) {
      const int n0 = half * 2, n1 = half * 2 + 1;

      i32x4 acc[4][2];
      {  // kk = 0: C = zf (no zero-init of acc needed)
        i32x4 b[2];
        #pragma unroll
        for (int n = 0; n < 2; ++n)
          b[n] = *reinterpret_cast<const i32x4*>(
              &Bs[cur][((0 + lkg) * 128 + wc * 64 + (n0 + n) * 16 + lrow) * 16]);
        #pragma unroll
        for (int mi = 0; mi < 4; ++mi)
          #pragma unroll
          for (int n = 0; n < 2; ++n)
            acc[mi][n] = __builtin_amdgcn_mfma_i32_16x16x64_i8(
                a[mi][0], b[n], zf, 0, 0, 0);
      }
      {  // kk = 1: chain
        i32x4 b[2];
        #pragma unroll
        for (int n = 0; n < 2; ++n)
          b[n] = *reinterpret_cast<const i32x4*>(
              &Bs[cur][((4 + lkg) * 128 + wc * 64 + (n0 + n) * 16 + lrow) * 16]);
        #pragma unroll
        for (int mi = 0; mi < 4; ++mi)
          #pragma unroll
          for (int n = 0; n < 2; ++n)
            acc[mi][n] = __builtin_amdgcn_mfma_i32_16x16x64_i8(
                a[mi][1], b[n], acc[mi][n], 0, 0, 0);
      }

      if (!mixed) {
        // FAST PATH (~97% of tiles): every pair is a negative -> pure max
        #pragma unroll
        for (int mi = 0; mi < 4; ++mi)
          #pragma unroll
          for (int r = 0; r < 4; ++r)
            an[mi][r] = imax3(an[mi][r], acc[mi][0][r], acc[mi][1][r]);
      } else if (diag) {
        #pragma unroll
        for (int mi = 0; mi < 4; ++mi)
          #pragma unroll
          for (int r = 0; r < 4; ++r) {
            int rl = (int)((rlbp[mi] >> (r * 8)) & 255u);
            int rloc = mi * 16 + lkg * 4 + r;
            int d0 = acc[mi][0][r], d1 = acc[mi][1][r];
            bool s0 = (rl == clb[n0]), s1 = (rl == clb[n1]);
            bool e0 = (rloc == n0 * 16 + lrow), e1 = (rloc == n1 * 16 + lrow);
            int p0 = (s0 && !e0) ? d0 : IMAX;
            int p1 = (s1 && !e1) ? d1 : IMAX;
            int q0 = s0 ? IMIN : d0;
            int q1 = s1 ? IMIN : d1;
            ap[mi][r] = imin3(ap[mi][r], p0, p1);
            an[mi][r] = imax3(an[mi][r], q0, q1);
          }
      } else {
        #pragma unroll
        for (int mi = 0; mi < 4; ++mi)
          #pragma unroll
          for (int r = 0; r < 4; ++r) {
            int rl = (int)((rlbp[mi] >> (r * 8)) & 255u);
            int d0 = acc[mi][0][r], d1 = acc[mi][1][r];
            bool s0 = (rl == clb[n0]), s1 = (rl == clb[n1]);
            int p0 = s0 ? d0 : IMAX;
            int p1 = s1 ? d1 : IMAX;
            int q0 = s0 ? IMIN : d0;
            int q1 = s1 ? IMIN : d1;
            ap[mi][r] = imin3(ap[mi][r], p0, p1);
            an[mi][r] = imax3(an[mi][r], q0, q1);
          }
      }
    }

    __syncthreads();   // drains staging vmcnt + publishes buf^1, protects reuse
    cur ^= 1;
  }

  // butterfly-reduce across the 16 lrow lanes sharing each C row, then one
  // device-scope atomic per row (fire-and-forget)
  #pragma unroll
  for (int mi = 0; mi < 4; ++mi)
    #pragma unroll
    for (int r = 0; r < 4; ++r) {
      int p = ap[mi][r], n = an[mi][r];
      #pragma unroll
      for (int off = 1; off < 16; off <<= 1) {
        p = min(p, __shfl_xor(p, off));
        n = max(n, __shfl_xor(n, off));
      }
      if (lrow == 0) {
        int rg = rowBase + mi * 16 + lkg * 4 + r;
        atomicMin(&ap_f[rg], p);
        atomicMax(&an_f[rg], n);
      }
    }
}

// ---------------- K3: single-block finalize (mean over rows is permutation-invariant) ----------------
__global__ __launch_bounds__(1024) void finalize_k(
    const int* __restrict__ ap_f, const int* __restrict__ an_f,
    const float* __restrict__ sqvS, float* __restrict__ out)
{
  int t = threadIdx.x;
  float sum = 0.f, cnt = 0.f;
  #pragma unroll
  for (int i = 0; i < BN / 1024; ++i) {
    int r = i * 1024 + t;
    int apt = ap_f[r], ant = an_f[r];
    if (apt != IMAX && ant != IMIN) {
      const float sc = 2.0f / (127.0f * 127.0f);
      float rs1 = sqvS[r] + 1.0f;
      float dap = sqrtf(fmaxf(fmaf(-sc, (float)apt, rs1), 0.f));
      float dan = sqrtf(fmaxf(fmaf(-sc, (float)ant, rs1), 0.f));
      sum += fmaxf(dap - dan + MARGIN_F, 0.f);
      cnt += 1.f;
    }
  }
  #pragma unroll
  for (int off = 32; off > 0; off >>= 1) {
    sum += __shfl_xor(sum, off);
    cnt += __shfl_xor(cnt, off);
  }
  __shared__ float ssum[16], scnt[16];
  int wv = t >> 6;
  if ((t & 63) == 0) { ssum[wv] = sum; scnt[wv] = cnt; }
  __syncthreads();
  if (t == 0) {
    float s = 0.f, c = 0.f;
    #pragma unroll
    for (int i = 0; i < 16; ++i) { s += ssum[i]; c += scnt[i]; }
    out[0] = (c > 0.f) ? (s / c) : 0.f;
  }
}

extern "C" void kernel_launch(void* const* d_in, const int* in_sizes, int n_in,
                              void* d_out, int out_size, void* d_ws, size_t ws_size,
                              hipStream_t stream)
{
  const float* emb = (const float*)d_in[0];
  const int*   lab = (const int*)d_in[1];
  float* out = (float*)d_out;
  float* ws  = (float*)d_ws;

  float* sqvS     = ws;                         // BN floats
  int*   ap_f     = (int*)(sqvS + BN);          // BN ints
  int*   an_f     = ap_f + BN;                  // BN ints
  int*   labS     = an_f + BN;                  // BN ints
  int*   binStart = labS + BN;                  // NLAB
  int*   binCur   = binStart + NLAB;            // NLAB
  char*  EnQ      = (char*)(binCur + NLAB + 16);// BN*DIM i8, k-major (~1 MB), 16B-aligned

  sort_prep_k<<<dim3(1), 1024, 0, stream>>>(lab, binStart, binCur);
  norm_cvt_k<<<dim3(BN / 4), 256, 0, stream>>>(emb, lab, sqvS, (unsigned short*)EnQ,
                                               labS, binCur, ap_f, an_f);
  gram_mine_mfma_k<<<dim3(BN / 128, NSPLIT), 256, 0, stream>>>(EnQ, labS, ap_f, an_f);
  finalize_k<<<dim3(1), 1024, 0, stream>>>(ap_f, an_f, sqvS, out);
}